// Round 5
// baseline (66.606 us; speedup 1.0000x reference)
//
#include <hip/hip_runtime.h>

// CostVolume via banded-correlation MFMA (v_mfma_f32_16x16x32_f16).
// cost[b,h,w,(sh+4)*9+(sw+4)] = LeakyReLU_0.1( mean_c x1[b,h,w,c]*warped[b,h+sh,w+sw,c] )
// B=8 H=128 W=192 C=128, MD=4. Output fp32 [B,H,W,81].
//
// Round-5 vs 59.7us round-4: cut ACCUMULATOR pressure by splitting the 9 sh
// values ACROSS WAVE PAIRS (not across time -- round 1's failure re-staged
// the halo 3x; this duplicates nothing block-level):
//   wave w: output row (w>>1), sh group (w&1): g0 = sh 0..4 (10 f32x4 acc),
//   g1 = sh 5..8 (8 f32x4). AGPR 72 -> 40. Combined regs <= arch+40 <= 128
//   even at arch 88 -> 4 waves/SIMD (2 fully resident blocks, 2 independent
//   barrier domains) vs 3 waves/SIMD (1.6 blocks) -- the round-3/4 cap.
// Block = 4 h-rows x 16 w-px, 8 waves, RH=12 staged rows, LDS 2x18.4 KB.
// Staging halo ratio 12/4 vs 16/8: +50% L2-side reads, HBM-absorbed (L3).
// Everything else as round 4: XCD swizzle (3072 = 8 x 384 = 8 images),
// direct band stores, lgkm-only barriers, conflict-free swizzled staging,
// K-chunks of 32 ch, double-buffered, depth-2 prefetch, rolling x1.

namespace {
constexpr int Bb = 8, Hh = 128, Ww = 192, Cn = 128;
constexpr int MDc = 4;
constexpr int TH = 4, TWT = 16;        // block tile: 4 rows x 16 px
constexpr int NTHR = 512;              // 8 waves = 4 rows x 2 sh-groups
constexpr int RH = TH + 8;             // 12 staged warped rows
constexpr int RPX = 24;                // staged warped px (w0-4 .. w0+19)
constexpr int KC = 32;                 // channels per chunk
constexpr int NCH = Cn / KC;           // 4
constexpr int KQB = RPX * 16;          // 384 B per kq-plane
constexpr int ROWB = 4 * KQB;          // 1536 B per staged row
constexpr int BUFB = RH * ROWB;        // 18432 B per buffer
constexpr int RUNS = RH * RPX * 4;     // 1152 8-channel runs per chunk
constexpr int NIT = 3;                 // it2 active only for tid<128
constexpr float NEG = 0.1f;
}

typedef __fp16 h2v   __attribute__((ext_vector_type(2)));
typedef __fp16 f16x8 __attribute__((ext_vector_type(8)));
typedef float  f32x4 __attribute__((ext_vector_type(4)));

__device__ __forceinline__ unsigned pkh2(float a, float b) {
    h2v h = __builtin_amdgcn_cvt_pkrtz(a, b);
    return __builtin_bit_cast(unsigned, h);
}

// Barrier with LDS-only drain: global prefetch loads stay in flight across it.
__device__ __forceinline__ void barrier_lgkm() {
    asm volatile("s_waitcnt lgkmcnt(0)\n\ts_barrier" ::: "memory");
}

__global__ __launch_bounds__(NTHR, 4)
void costvol_mfma(const float* __restrict__ x1,
                  const float* __restrict__ wp,
                  float* __restrict__ out)
{
    __shared__ __align__(16) unsigned char smem[2 * BUFB];   // 36864 B

    const int tid  = threadIdx.x;
    const int w    = tid >> 6;        // wave 0..7
    const int wvr  = w >> 1;          // output row within tile: 0..3
    const int shb  = (w & 1) * 5;     // sh group base: 0 or 5
    const int shn  = 5 - (w & 1);     // sh count: 5 (g0) or 4 (g1)
    const int lane = tid & 63;
    const int nI   = lane & 15;       // A-row m / B-col n lane index
    const int kq   = lane >> 4;       // 0..3 : k-group (8 channels each)

    // XCD swizzle: 3072 wg = 8 XCDs x 384; 384 = one batch image (12 x 32).
    const int id = blockIdx.x;
    const int wg = (id & 7) * 384 + (id >> 3);
    const int bx = wg % 12;
    const int t2 = wg / 12;           // 0..255
    const int by = t2 & 31;
    const int bz = t2 >> 5;

    const int w0 = bx * TWT;
    const int h0 = by * TH;
    const int b  = bz;

    // ---- warped staging decode: run = (row, px, kq), kq innermost ----
    int g_off[NIT]; int l_off[NIT]; bool g_ok[NIT];
#pragma unroll
    for (int it = 0; it < NIT; ++it) {
        int s   = tid + it * NTHR;    // 0..1535; valid < 1152
        int skq = s & 3;
        int t   = s >> 2;             // 0..383
        int px  = t % RPX;
        int row = t / RPX;            // 0..15 (valid < 12)
        int hw  = h0 - MDc + row;
        int ww  = w0 - MDc + px;
        bool ok = (s < RUNS) &&
                  (unsigned)hw < (unsigned)Hh && (unsigned)ww < (unsigned)Ww;
        g_ok[it]  = ok;
        g_off[it] = ((b * Hh + (ok ? hw : 0)) * Ww + (ok ? ww : 0)) * Cn + skq * 8;
        l_off[it] = row * ROWB + skq * KQB + ((px ^ (skq << 1)) * 16);
    }

    uint4 gp[NIT];
    auto LOADCH = [&](int ch) {
#pragma unroll
        for (int it = 0; it < NIT; ++it) {
            if (g_ok[it]) {
                const float* p = wp + g_off[it] + ch * KC;
                float4 u = *reinterpret_cast<const float4*>(p);
                float4 v = *reinterpret_cast<const float4*>(p + 4);
                gp[it] = make_uint4(pkh2(u.x, u.y), pkh2(u.z, u.w),
                                    pkh2(v.x, v.y), pkh2(v.z, v.w));
            } else {
                gp[it] = make_uint4(0u, 0u, 0u, 0u);
            }
        }
    };
    auto WRITEB = [&](int buf) {
        *reinterpret_cast<uint4*>(smem + buf * BUFB + l_off[0]) = gp[0];
        *reinterpret_cast<uint4*>(smem + buf * BUFB + l_off[1]) = gp[1];
        if (tid < RUNS - 2 * NTHR)    // it2 exists only for tid<128
            *reinterpret_cast<uint4*>(smem + buf * BUFB + l_off[2]) = gp[2];
    };

    // issue first staging chunk before x1 loads (staging is the critical path)
    LOADCH(0);

    // ---- x1 rolling raw prefetch: 8 VGPRs hold next chunk's fp32 data ----
    const float* xp = x1 + ((size_t)((b * Hh + h0 + wvr) * Ww) + w0 + nI) * Cn + kq * 8;
    float4 ar_u, ar_v;                 // raw x1 data for the upcoming chunk
    ar_u = *reinterpret_cast<const float4*>(xp);
    ar_v = *reinterpret_cast<const float4*>(xp + 4);

    f32x4 ac0[5], ac1[5];
#pragma unroll
    for (int s = 0; s < 5; ++s) {
        f32x4 z = {0.f, 0.f, 0.f, 0.f};
        ac0[s] = z; ac1[s] = z;
    }

    // per-lane B fragment offset within a staged row; tile1 = ro0 + 128
    const int ro0 = kq * KQB + ((nI ^ (kq << 1)) * 16);

    WRITEB(0); LOADCH(1);

    int cur = 0;
#pragma unroll
    for (int ch = 0; ch < NCH; ++ch) {
        barrier_lgkm();
        if (ch + 1 < NCH) WRITEB(cur ^ 1);
        if (ch + 2 < NCH) LOADCH(ch + 2);
        // convert this chunk's x1 (loaded last step), then issue next chunk
        uint4 afr = make_uint4(pkh2(ar_u.x, ar_u.y), pkh2(ar_u.z, ar_u.w),
                               pkh2(ar_v.x, ar_v.y), pkh2(ar_v.z, ar_v.w));
        if (ch + 1 < NCH) {
            ar_u = *reinterpret_cast<const float4*>(xp + (ch + 1) * KC);
            ar_v = *reinterpret_cast<const float4*>(xp + (ch + 1) * KC + 4);
        }
        f16x8 av = __builtin_bit_cast(f16x8, afr);
        const unsigned char* base = smem + cur * BUFB;
#pragma unroll
        for (int s = 0; s < 5; ++s) {
            if (s < shn) {
                // staged row = wvr + (shb + s); g1 reads rows wvr+5..wvr+8
                const unsigned char* rp = base + (wvr + shb + s) * ROWB;
                uint4 b0 = *reinterpret_cast<const uint4*>(rp + ro0);
                uint4 b1 = *reinterpret_cast<const uint4*>(rp + ro0 + 128);
                ac0[s] = __builtin_amdgcn_mfma_f32_16x16x32_f16(
                    av, __builtin_bit_cast(f16x8, b0), ac0[s], 0, 0, 0);
                ac1[s] = __builtin_amdgcn_mfma_f32_16x16x32_f16(
                    av, __builtin_bit_cast(f16x8, b1), ac1[s], 0, 0, 0);
            }
        }
        cur ^= 1;
    }

    // ---- direct band stores: no LDS round-trip, no barriers ----
    // C/D map: col=n=lane&15, row=m=(lane>>4)*4+reg
    // tile0: staged px p = nI      -> (m, sw4 = nI-m),   valid d=nI-m in [0,8]
    // tile1: staged px p = nI + 8  -> (m, sw4 = nI-m+8), valid d in [-8,0] && nI>=8
    // out k-index = (shb+s)*9 + sw4; wave groups write disjoint k ranges.
    const float sc = 1.0f / (float)Cn;
    const size_t rowbase = ((size_t)((b * Hh + h0 + wvr) * Ww) + w0) * 81;
#pragma unroll
    for (int rg = 0; rg < 4; ++rg) {
        int m = kq * 4 + rg;
        int d = nI - m;
        bool t0 = (d >= 0 && d <= 8);
        bool t1 = (d >= -8 && d <= 0 && nI >= 8);
        size_t mb = rowbase + (size_t)m * 81 + shb * 9;
#pragma unroll
        for (int s = 0; s < 5; ++s) {
            if (s < shn) {
                if (t0) {
                    float v = ac0[s][rg] * sc;
                    v = (v >= 0.f) ? v : NEG * v;
                    out[mb + s * 9 + d] = v;
                }
                if (t1) {
                    float v = ac1[s][rg] * sc;
                    v = (v >= 0.f) ? v : NEG * v;
                    out[mb + s * 9 + d + 8] = v;
                }
            }
        }
    }
}

extern "C" void kernel_launch(void* const* d_in, const int* in_sizes, int n_in,
                              void* d_out, int out_size, void* d_ws, size_t ws_size,
                              hipStream_t stream) {
    const float* x1 = (const float*)d_in[0];
    const float* wp = (const float*)d_in[1];
    float* out = (float*)d_out;
    dim3 grid(12 * 32 * 8, 1, 1);   // 3072 blocks, XCD-swizzled in-kernel
    costvol_mfma<<<grid, NTHR, 0, stream>>>(x1, wp, out);
}